// Round 1
// baseline (74.194 us; speedup 1.0000x reference)
//
#include <hip/hip_runtime.h>

// Per-a batched GEMM:  for a in [0,1024):
//   Yre[b,k] = sum_j Xre[b,j]*hr1[a,j,k] + Xim[b,j]*hi1[a,j,k]
//   Yim[b,k] = sum_j Xre[b,j]*hi2[a,j,k] + Xim[b,j]*hr2[a,j,k]
// where X is the row-permuted input reshaped (B=16, 2, 1024, 128).
//
// Block = one 'a' (grid 1024, 128 threads = 2 waves).
//   wave 0 -> re channel (reads hr1,hi1), wave 1 -> im channel (hi2,hr2)
//   lane: bh = lane>>5 (b-half), kg = lane&31 -> k0 = 4*kg (float4 over k)
//   acc[8] float4 = 8 b x 4 k per lane. H streamed from HBM exactly once.
// x (16 KB per a) staged in LDS as x_lds[j*32 + c*16 + b], broadcast-read.

__global__ __launch_bounds__(128, 2)
void hmat_kernel(const float* __restrict__ x,
                 const float* __restrict__ hr1,
                 const float* __restrict__ hi1,
                 const float* __restrict__ hr2,
                 const float* __restrict__ hi2,
                 const int* __restrict__ perm,
                 float* __restrict__ out) {
  __shared__ float x_lds[4096];  // [j=128][c=2][b=16]
  const int a = blockIdx.x;
  const int t = threadIdx.x;

  // ---- stage permuted x into LDS: 128 threads x 32 floats ----
  {
    const int b  = t >> 3;        // 0..15
    const int c  = (t >> 2) & 1;  // 0..1
    const int jg = t & 3;         // 0..3 (row group within a)
    const int row = perm[a * 4 + jg];
    const float4* src =
        (const float4*)(x + ((size_t)(b * 2 + c) * 4096 + (size_t)row) * 32);
#pragma unroll
    for (int q = 0; q < 8; ++q) {
      const float4 v = src[q];
      const int jb = jg * 32 + q * 4;
      x_lds[(jb + 0) * 32 + c * 16 + b] = v.x;
      x_lds[(jb + 1) * 32 + c * 16 + b] = v.y;
      x_lds[(jb + 2) * 32 + c * 16 + b] = v.z;
      x_lds[(jb + 3) * 32 + c * 16 + b] = v.w;
    }
  }
  __syncthreads();

  const int ch   = t >> 6;   // wave index = output channel
  const int lane = t & 63;
  const int bh   = lane >> 5;
  const int kg   = lane & 31;
  const int k0   = kg * 4;
  const int b0   = bh * 8;

  const float* __restrict__ H1 = (ch == 0 ? hr1 : hi2) + (size_t)a * 16384;
  const float* __restrict__ H2 = (ch == 0 ? hi1 : hr2) + (size_t)a * 16384;

  float4 acc[8];
#pragma unroll
  for (int i = 0; i < 8; ++i) acc[i] = make_float4(0.f, 0.f, 0.f, 0.f);

#pragma unroll 4
  for (int j = 0; j < 128; ++j) {
    const float4 h1 = *(const float4*)(H1 + j * 128 + k0);
    const float4 h2 = *(const float4*)(H2 + j * 128 + k0);
    const float4 xr0 = *(const float4*)&x_lds[j * 32 + b0];
    const float4 xr1 = *(const float4*)&x_lds[j * 32 + b0 + 4];
    const float4 xi0 = *(const float4*)&x_lds[j * 32 + 16 + b0];
    const float4 xi1 = *(const float4*)&x_lds[j * 32 + 16 + b0 + 4];
    const float xr[8] = {xr0.x, xr0.y, xr0.z, xr0.w, xr1.x, xr1.y, xr1.z, xr1.w};
    const float xi[8] = {xi0.x, xi0.y, xi0.z, xi0.w, xi1.x, xi1.y, xi1.z, xi1.w};
#pragma unroll
    for (int bb = 0; bb < 8; ++bb) {
      acc[bb].x = fmaf(xr[bb], h1.x, fmaf(xi[bb], h2.x, acc[bb].x));
      acc[bb].y = fmaf(xr[bb], h1.y, fmaf(xi[bb], h2.y, acc[bb].y));
      acc[bb].z = fmaf(xr[bb], h1.z, fmaf(xi[bb], h2.z, acc[bb].z));
      acc[bb].w = fmaf(xr[bb], h1.w, fmaf(xi[bb], h2.w, acc[bb].w));
    }
  }

  // ---- epilogue: out[(b*2+ch)*131072 + a*128 + k] ----
#pragma unroll
  for (int bb = 0; bb < 8; ++bb) {
    const int b = b0 + bb;
    float4* dst =
        (float4*)(out + (size_t)(b * 2 + ch) * 131072 + (size_t)a * 128 + k0);
    *dst = acc[bb];
  }
}

extern "C" void kernel_launch(void* const* d_in, const int* in_sizes, int n_in,
                              void* d_out, int out_size, void* d_ws, size_t ws_size,
                              hipStream_t stream) {
  const float* x   = (const float*)d_in[0];
  const float* hr1 = (const float*)d_in[1];
  const float* hi1 = (const float*)d_in[2];
  const float* hr2 = (const float*)d_in[3];
  const float* hi2 = (const float*)d_in[4];
  const int* perm  = (const int*)d_in[5];
  float* out = (float*)d_out;

  hipLaunchKernelGGL(hmat_kernel, dim3(1024), dim3(128), 0, stream,
                     x, hr1, hi1, hr2, hi2, perm, out);
}

// Round 2
// 69.160 us; speedup vs baseline: 1.0728x; 1.0728x over previous
//
#include <hip/hip_runtime.h>

// Per-a batched GEMM:  for a in [0,1024):
//   Yre[b,k] = sum_j Xre[b,j]*hr1[a,j,k] + Xim[b,j]*hi1[a,j,k]
//   Yim[b,k] = sum_j Xre[b,j]*hi2[a,j,k] + Xim[b,j]*hr2[a,j,k]
// X is the row-permuted input reshaped (B=16, 2, 1024, 128).
//
// Block = one 'a', 256 threads = 4 waves (was 2 — latency-bound at 20% occ).
//   wave = (ch = t>>7, b-half = (t>>5)&3): lane accumulates 4 b x 4 k.
//   H rows are read by 2 waves per channel -> duplicate reads served by L1/L2,
//   HBM traffic unchanged; outstanding-load count doubled.

__global__ __launch_bounds__(256, 4)
void hmat_kernel(const float* __restrict__ x,
                 const float* __restrict__ hr1,
                 const float* __restrict__ hi1,
                 const float* __restrict__ hr2,
                 const float* __restrict__ hi2,
                 const int* __restrict__ perm,
                 float* __restrict__ out) {
  __shared__ float x_lds[4096];  // [j=128][c=2][b=16]
  const int a = blockIdx.x;
  const int t = threadIdx.x;

  // ---- stage permuted x into LDS: 256 threads x 16 floats ----
  {
    const int b    = t >> 4;        // 0..15
    const int c    = (t >> 3) & 1;  // 0..1
    const int jg   = (t >> 1) & 3;  // 0..3 (row group within a)
    const int half = t & 1;         // 0..1
    const int row  = perm[a * 4 + jg];
    const float4* src =
        (const float4*)(x + ((size_t)(b * 2 + c) * 4096 + (size_t)row) * 32 +
                        half * 16);
#pragma unroll
    for (int q = 0; q < 4; ++q) {
      const float4 v = src[q];
      const int jb = jg * 32 + half * 16 + q * 4;
      x_lds[(jb + 0) * 32 + c * 16 + b] = v.x;
      x_lds[(jb + 1) * 32 + c * 16 + b] = v.y;
      x_lds[(jb + 2) * 32 + c * 16 + b] = v.z;
      x_lds[(jb + 3) * 32 + c * 16 + b] = v.w;
    }
  }
  __syncthreads();

  const int ch = t >> 7;         // output channel (wave pair)
  const int u  = t & 127;
  const int bh = u >> 5;         // 0..3
  const int b0 = bh * 4;
  const int kg = u & 31;
  const int k0 = kg * 4;

  const float* __restrict__ H1 = (ch == 0 ? hr1 : hi2) + (size_t)a * 16384;
  const float* __restrict__ H2 = (ch == 0 ? hi1 : hr2) + (size_t)a * 16384;

  float4 acc[4];
#pragma unroll
  for (int i = 0; i < 4; ++i) acc[i] = make_float4(0.f, 0.f, 0.f, 0.f);

#pragma unroll 4
  for (int j = 0; j < 128; ++j) {
    const float4 h1 = *(const float4*)(H1 + j * 128 + k0);
    const float4 h2 = *(const float4*)(H2 + j * 128 + k0);
    const float4 xr4 = *(const float4*)&x_lds[j * 32 + b0];
    const float4 xi4 = *(const float4*)&x_lds[j * 32 + 16 + b0];
    const float xr[4] = {xr4.x, xr4.y, xr4.z, xr4.w};
    const float xi[4] = {xi4.x, xi4.y, xi4.z, xi4.w};
#pragma unroll
    for (int bb = 0; bb < 4; ++bb) {
      acc[bb].x = fmaf(xr[bb], h1.x, fmaf(xi[bb], h2.x, acc[bb].x));
      acc[bb].y = fmaf(xr[bb], h1.y, fmaf(xi[bb], h2.y, acc[bb].y));
      acc[bb].z = fmaf(xr[bb], h1.z, fmaf(xi[bb], h2.z, acc[bb].z));
      acc[bb].w = fmaf(xr[bb], h1.w, fmaf(xi[bb], h2.w, acc[bb].w));
    }
  }

  // ---- epilogue: out[(b*2+ch)*131072 + a*128 + k] ----
#pragma unroll
  for (int bb = 0; bb < 4; ++bb) {
    const int b = b0 + bb;
    float4* dst =
        (float4*)(out + (size_t)(b * 2 + ch) * 131072 + (size_t)a * 128 + k0);
    *dst = acc[bb];
  }
}

extern "C" void kernel_launch(void* const* d_in, const int* in_sizes, int n_in,
                              void* d_out, int out_size, void* d_ws, size_t ws_size,
                              hipStream_t stream) {
  const float* x   = (const float*)d_in[0];
  const float* hr1 = (const float*)d_in[1];
  const float* hi1 = (const float*)d_in[2];
  const float* hr2 = (const float*)d_in[3];
  const float* hi2 = (const float*)d_in[4];
  const int* perm  = (const int*)d_in[5];
  float* out = (float*)d_out;

  hipLaunchKernelGGL(hmat_kernel, dim3(1024), dim3(256), 0, stream,
                     x, hr1, hi1, hr2, hi2, perm, out);
}

// Round 3
// 57.190 us; speedup vs baseline: 1.2973x; 1.2093x over previous
//
#include <hip/hip_runtime.h>

// Per-a batched GEMM, each H element read EXACTLY ONCE from memory:
//   Yre[b,k] = sum_j Xre[b,j]*hr1[a,j,k] + Xim[b,j]*hi1[a,j,k]
//   Yim[b,k] = sum_j Xre[b,j]*hi2[a,j,k] + Xim[b,j]*hr2[a,j,k]
//
// Block = one 'a', 256 threads = 4 waves: wave = (ch = w>>1, jh = w&1).
//   Lane: m = lane>>5 selects the matrix of the pair (and x channel, c==m),
//         kg = lane&31 -> k0 = 4*kg.
//   Each lane accumulates ALL 16 b for its 4 k (64 VGPR acc) -> each H row
//   is touched by one half-wave exactly once (no duplicate L1/L2 traffic).
//   4-deep explicit prefetch ring (static indices) keeps 4 KB/wave in flight.
// Epilogue: shfl-fold m-halves (lane^32), LDS-reduce jh-halves (reuses x buf).

__global__ __launch_bounds__(256, 4)
void hmat_kernel(const float* __restrict__ x,
                 const float* __restrict__ hr1,
                 const float* __restrict__ hi1,
                 const float* __restrict__ hr2,
                 const float* __restrict__ hi2,
                 const int* __restrict__ perm,
                 float* __restrict__ out) {
  __shared__ float lds[4096];  // x stage [j*32 + c*16 + b]; then reduce buf
  const int a = blockIdx.x;
  const int t = threadIdx.x;

  // ---- stage permuted x into LDS: 256 threads x 16 floats ----
  {
    const int b    = t >> 4;        // 0..15
    const int c    = (t >> 3) & 1;  // 0..1
    const int jg   = (t >> 1) & 3;  // 0..3 (row group within a)
    const int half = t & 1;         // 0..1
    const int row  = perm[a * 4 + jg];
    const float4* src =
        (const float4*)(x + ((size_t)(b * 2 + c) * 4096 + (size_t)row) * 32 +
                        half * 16);
#pragma unroll
    for (int q = 0; q < 4; ++q) {
      const float4 v = src[q];
      const int jb = jg * 32 + half * 16 + q * 4;
      lds[(jb + 0) * 32 + c * 16 + b] = v.x;
      lds[(jb + 1) * 32 + c * 16 + b] = v.y;
      lds[(jb + 2) * 32 + c * 16 + b] = v.z;
      lds[(jb + 3) * 32 + c * 16 + b] = v.w;
    }
  }
  __syncthreads();

  const int w    = t >> 6;   // wave 0..3
  const int ch   = w >> 1;   // output channel
  const int jh   = w & 1;    // j half: [0,64) or [64,128)
  const int lane = t & 63;
  const int m    = lane >> 5;  // matrix of the pair; x channel c == m
  const int kg   = lane & 31;
  const int k0   = kg * 4;

  const float* __restrict__ Hm =
      (ch == 0) ? (m == 0 ? hr1 : hi1) : (m == 0 ? hi2 : hr2);
  const float* __restrict__ hp =
      Hm + (size_t)a * 16384 + (size_t)jh * 8192 + k0;
  const float* __restrict__ xp = lds + jh * 2048 + m * 16;

  float4 acc[16];
#pragma unroll
  for (int i = 0; i < 16; ++i) acc[i] = make_float4(0.f, 0.f, 0.f, 0.f);

  // 4-deep prefetch ring, static register names (no runtime indexing)
  float4 pf0 = *(const float4*)(hp + 0 * 128);
  float4 pf1 = *(const float4*)(hp + 1 * 128);
  float4 pf2 = *(const float4*)(hp + 2 * 128);
  float4 pf3 = *(const float4*)(hp + 3 * 128);

#define CONSUME(PF, J)                                                     \
  {                                                                        \
    const float* xj = xp + (J) * 32;                                       \
    const float4 xa = *(const float4*)(xj + 0);                            \
    const float4 xb = *(const float4*)(xj + 4);                            \
    const float4 xc = *(const float4*)(xj + 8);                            \
    const float4 xd = *(const float4*)(xj + 12);                           \
    const float xs[16] = {xa.x, xa.y, xa.z, xa.w, xb.x, xb.y, xb.z, xb.w,  \
                          xc.x, xc.y, xc.z, xc.w, xd.x, xd.y, xd.z, xd.w}; \
    _Pragma("unroll") for (int bb = 0; bb < 16; ++bb) {                    \
      acc[bb].x = fmaf(xs[bb], (PF).x, acc[bb].x);                         \
      acc[bb].y = fmaf(xs[bb], (PF).y, acc[bb].y);                         \
      acc[bb].z = fmaf(xs[bb], (PF).z, acc[bb].z);                         \
      acc[bb].w = fmaf(xs[bb], (PF).w, acc[bb].w);                         \
    }                                                                      \
  }

  for (int j4 = 0; j4 < 60; j4 += 4) {
    CONSUME(pf0, j4 + 0); pf0 = *(const float4*)(hp + (j4 + 4) * 128);
    CONSUME(pf1, j4 + 1); pf1 = *(const float4*)(hp + (j4 + 5) * 128);
    CONSUME(pf2, j4 + 2); pf2 = *(const float4*)(hp + (j4 + 6) * 128);
    CONSUME(pf3, j4 + 3); pf3 = *(const float4*)(hp + (j4 + 7) * 128);
  }
  CONSUME(pf0, 60);
  CONSUME(pf1, 61);
  CONSUME(pf2, 62);
  CONSUME(pf3, 63);
#undef CONSUME

  // ---- fold the two matrix-halves: lane p += lane p^32 ----
#pragma unroll
  for (int bb = 0; bb < 16; ++bb) {
    acc[bb].x += __shfl_xor(acc[bb].x, 32, 64);
    acc[bb].y += __shfl_xor(acc[bb].y, 32, 64);
    acc[bb].z += __shfl_xor(acc[bb].z, 32, 64);
    acc[bb].w += __shfl_xor(acc[bb].w, 32, 64);
  }

  // ---- reduce the two j-halves via LDS (reuse x buffer) ----
  __syncthreads();  // all waves done reading x
  if (jh == 1 && m == 0) {
#pragma unroll
    for (int bb = 0; bb < 16; ++bb)
      *(float4*)&lds[ch * 2048 + bb * 128 + k0] = acc[bb];
  }
  __syncthreads();
  if (jh == 0 && m == 0) {
#pragma unroll
    for (int bb = 0; bb < 16; ++bb) {
      const float4 o = *(const float4*)&lds[ch * 2048 + bb * 128 + k0];
      float4 r;
      r.x = acc[bb].x + o.x;
      r.y = acc[bb].y + o.y;
      r.z = acc[bb].z + o.z;
      r.w = acc[bb].w + o.w;
      *(float4*)(out + (size_t)(bb * 2 + ch) * 131072 + (size_t)a * 128 + k0) =
          r;
    }
  }
}

extern "C" void kernel_launch(void* const* d_in, const int* in_sizes, int n_in,
                              void* d_out, int out_size, void* d_ws, size_t ws_size,
                              hipStream_t stream) {
  const float* x   = (const float*)d_in[0];
  const float* hr1 = (const float*)d_in[1];
  const float* hi1 = (const float*)d_in[2];
  const float* hr2 = (const float*)d_in[3];
  const float* hi2 = (const float*)d_in[4];
  const int* perm  = (const int*)d_in[5];
  float* out = (float*)d_out;

  hipLaunchKernelGGL(hmat_kernel, dim3(1024), dim3(256), 0, stream,
                     x, hr1, hi1, hr2, hi2, perm, out);
}